// Round 1
// 333.580 us; speedup vs baseline: 1.0046x; 1.0046x over previous
//
#include <hip/hip_runtime.h>
#include <math.h>

#define T_LEN 65536

#define DROW 72      // bf16 words per staged data row (64 + 8 pad)
#define SLOT 324     // 32-bit words per per-t LDS tile slot (16 x 20 + 4 pad)
#define RSA 20       // row/col stride (words) inside a slot
#define BSTR 24      // shorts per B row
#define BSLOT 392    // shorts per B tile (16 x 24 + 8 pad)
#define BWAVE 2592   // shorts per wave's B range (== 4 Gc slots)
#define K2 16        // stage-2 chunk length
#define W2 24        // stage-2 warm-up steps
#define PF 8         // stage-2 prefetch depth

typedef __attribute__((ext_vector_type(8))) short bh8;
typedef __attribute__((ext_vector_type(4))) float f4;

__device__ __forceinline__ unsigned short f2bf(float x) {
    union { float f; unsigned u; } v; v.f = x;
    return (unsigned short)((v.u + 0x7FFFu + ((v.u >> 16) & 1u)) >> 16);  // RNE
}
__device__ __forceinline__ float bf2f(unsigned short s) {
    union { unsigned u; float f; } v; v.u = ((unsigned)s) << 16; return v.f;
}
// pack hi/lo bf16 split of a float into one u32 (hi in low 16, lo in high 16)
__device__ __forceinline__ unsigned packhl(float x) {
    unsigned short h = f2bf(x);
    float r = x - bf2f(h);
    unsigned short l = f2bf(r);
    return (unsigned)h | ((unsigned)l << 16);
}
// unpack 8 packed u32 -> bh8 of hi parts and bh8 of lo parts
__device__ __forceinline__ void unpk8(const uint4 a, const uint4 b, bh8& hi, bh8& lo) {
    union { unsigned u[4]; bh8 v; } H, L;
    H.u[0] = (a.x & 0xffffu) | (a.y << 16);
    H.u[1] = (a.z & 0xffffu) | (a.w << 16);
    H.u[2] = (b.x & 0xffffu) | (b.y << 16);
    H.u[3] = (b.z & 0xffffu) | (b.w << 16);
    L.u[0] = (a.x >> 16) | (a.y & 0xffff0000u);
    L.u[1] = (a.z >> 16) | (a.w & 0xffff0000u);
    L.u[2] = (b.x >> 16) | (b.y & 0xffff0000u);
    L.u[3] = (b.z >> 16) | (b.w & 0xffff0000u);
    hi = H.v; lo = L.v;
}

// ---- one-time weight swizzle into bf16 MFMA B-fragment order ----
__global__ void wswz_kernel(const float* __restrict__ Wmu, const float* __restrict__ WL,
                            const float* __restrict__ WLx, short* __restrict__ Wsw)
{
    int idx = blockIdx.x * 256 + threadIdx.x;   // 0 .. 66*512-1
    int f = idx >> 9, r = idx & 511;
    int lane = r >> 3, j = r & 7;
    int ks = f & 1, job = f >> 1;
    int k = ks * 32 + ((lane >> 4) << 3) + j;
    int n = job * 16 + (lane & 15);
    float v = (n < 16) ? Wmu[k * 16 + n]
            : (n < 272) ? WL[k * 256 + (n - 16)]
            : WLx[k * 256 + (n - 272)];
    Wsw[idx] = (short)f2bf(v);
}

// ---- fused: recognition GEMM -> MFMA tile algebra -> serial chol/Y-solve ----
// Per t:  S = A A^T + eps I        (MFMA, bf16x3 split)
//         C1n = -(B A^T)           (MFMA; B already bf16, A split -> near-exact)
//         G = chol(S)              (serial, 16-lane group, LDS column broadcast)
//         Y = G^{-T}, u = G^{-T}ns (serial backward solve; Y columns lane-local)
//         W = Y Y^T                (MFMA Gram, via LDS transpose of Y)
//         N^T = C1n * W            (MFMA)  [= -G^{-T} C^T with reference C]
// All post-barrier dataflow is wave-local: wave wv owns t = t0 + 4*wv .. +3.
__global__ __launch_bounds__(256, 3)
void vilds_fused(const float* __restrict__ data, const short* __restrict__ Wsw,
                 const float* __restrict__ bmu, const float* __restrict__ bL,
                 const float* __restrict__ bLx, const float* __restrict__ ns,
                 unsigned short* __restrict__ Nbuf, float* __restrict__ Ubuf,
                 float* __restrict__ PXbuf, float* __restrict__ entOut)
{
    __shared__ short Dt[17 * DROW];                              // staged data rows
    __shared__ unsigned int Agl[16 * SLOT];                      // A packed hi|lo -> later -C1 packed
    __shared__ __align__(16) unsigned char GcRaw[16 * SLOT * 4]; // B tiles -> S cols -> resid cols -> Y cols
    __shared__ unsigned int Yp[4 * SLOT];                        // per-wave scratch: Yrow packed -> W packed

    float* Gc = (float*)GcRaw;
    short* Bsh = (short*)GcRaw;

    const int tid = threadIdx.x;
    const int t0 = blockIdx.x * 16;

    // stage data rows t0..t0+16 as bf16
    for (int idx = tid; idx < 17 * 16; idx += 256) {
        int row = idx >> 4, c4 = idx & 15;
        int tr = t0 + row;
        float4 dv = (tr < T_LEN) ? ((const float4*)data)[(size_t)tr * 16 + c4]
                                 : make_float4(0.f, 0.f, 0.f, 0.f);
        short4 b;
        b.x = (short)f2bf(dv.x); b.y = (short)f2bf(dv.y);
        b.z = (short)f2bf(dv.z); b.w = (short)f2bf(dv.w);
        *(short4*)&Dt[row * DROW + c4 * 4] = b;
    }
    __syncthreads();

    const int wv = tid >> 6, lane = tid & 63;
    const int col = lane & 15, quad = lane >> 4;

    // ---- recognition GEMM: jobs 0=postX, 1..16=A rows (hi/lo split), 17..32=B rows ----
    {
        bh8 a00 = *(const bh8*)&Dt[col * DROW + quad * 8];
        bh8 a01 = *(const bh8*)&Dt[col * DROW + quad * 8 + 32];
        bh8 a10 = *(const bh8*)&Dt[(col + 1) * DROW + quad * 8];
        bh8 a11 = *(const bh8*)&Dt[(col + 1) * DROW + quad * 8 + 32];
        for (int job = wv; job < 33; job += 4) {
            const int isB = (job >= 17);
            bh8 b0 = *(const bh8*)&Wsw[(job * 2 + 0) * 512 + lane * 8];
            bh8 b1 = *(const bh8*)&Wsw[(job * 2 + 1) * 512 + lane * 8];
            float bias;
            if (job == 0)      bias = bmu[col];
            else if (!isB)     bias = bL[(job - 1) * 16 + col] + ((col == job - 1) ? 3.0f : 0.0f);
            else               bias = bLx[(job - 17) * 16 + col];
            f4 acc = { bias, bias, bias, bias };
            acc = __builtin_amdgcn_mfma_f32_16x16x32_bf16(isB ? a10 : a00, b0, acc, 0, 0, 0);
            acc = __builtin_amdgcn_mfma_f32_16x16x32_bf16(isB ? a11 : a01, b1, acc, 0, 0, 0);
            if (job == 0) {
                #pragma unroll
                for (int r = 0; r < 4; ++r)
                    PXbuf[(size_t)(t0 + quad * 4 + r) * 16 + col] = acc[r];
            } else if (!isB) {
                int i = job - 1;
                #pragma unroll
                for (int r = 0; r < 4; ++r)
                    Agl[(quad * 4 + r) * SLOT + i * RSA + col] = packhl(acc[r]);
            } else {
                int i = job - 17;
                #pragma unroll
                for (int r = 0; r < 4; ++r) {
                    int tw = quad * 4 + r;
                    Bsh[(tw >> 2) * BWAVE + (tw & 3) * BSLOT + i * BSTR + col] = (short)f2bf(acc[r]);
                }
            }
        }
    }
    __syncthreads();

    const bh8 zero8 = (bh8){0, 0, 0, 0, 0, 0, 0, 0};

    // ---- per-wave MFMA: S (col-major into Gc) and -C1 (packed row-major into Agl) ----
    {
        bh8 bfr[4]; uint4 au0[4], au1[4];
        #pragma unroll
        for (int tt = 0; tt < 4; ++tt) {
            int sl = wv * 4 + tt;
            bfr[tt] = *(const bh8*)&Bsh[wv * BWAVE + tt * BSLOT + col * BSTR + (quad & 1) * 8];
            au0[tt] = *(const uint4*)&Agl[sl * SLOT + col * RSA + (quad & 1) * 8];
            au1[tt] = *(const uint4*)&Agl[sl * SLOT + col * RSA + (quad & 1) * 8 + 4];
        }
        asm volatile("s_waitcnt lgkmcnt(0)" ::: "memory");  // all reads landed before overlay writes
        #pragma unroll
        for (int tt = 0; tt < 4; ++tt) {
            int sl = wv * 4 + tt;
            bh8 hi8, lo8; unpk8(au0[tt], au1[tt], hi8, lo8);
            bh8 fa = (quad < 2) ? hi8 : lo8;                 // [Ahi | Alo]
            f4 accS = { (quad * 4 + 0 == col) ? 1e-6f : 0.f, (quad * 4 + 1 == col) ? 1e-6f : 0.f,
                        (quad * 4 + 2 == col) ? 1e-6f : 0.f, (quad * 4 + 3 == col) ? 1e-6f : 0.f };
            // S = hi hi^T + lo hi^T + hi lo^T  (+ eps I)
            accS = __builtin_amdgcn_mfma_f32_16x16x32_bf16(fa, hi8, accS, 0, 0, 0);
            accS = __builtin_amdgcn_mfma_f32_16x16x32_bf16(hi8, (quad < 2) ? lo8 : zero8, accS, 0, 0, 0);
            // C1 = B * A^T  (exact split on A side)
            f4 accC = { 0.f, 0.f, 0.f, 0.f };
            accC = __builtin_amdgcn_mfma_f32_16x16x32_bf16(bfr[tt], fa, accC, 0, 0, 0);
            // store S column-major (symmetric): Gc[col*RSA + row]
            *(f4*)&Gc[sl * SLOT + col * RSA + quad * 4] = accS;
            // store -C1 row-major, hi/lo packed (overlays A slot; A reads hoisted above)
            #pragma unroll
            for (int r = 0; r < 4; ++r)
                Agl[sl * SLOT + (quad * 4 + r) * RSA + col] = packhl(-accC[r]);
        }
    }

    // ---- serial factorization: group gg (16 lanes) handles t = t0 + gg ----
    const int gg = tid >> 4, li = tid & 15;
    const int t = t0 + gg;
    float* Gt = &Gc[gg * SLOT];

    float s[16];
    #pragma unroll
    for (int c = 0; c < 4; ++c) {
        f4 v = *(const f4*)&Gt[li * RSA + c * 4];   // S column li == row li
        s[4 * c + 0] = v[0]; s[4 * c + 1] = v[1]; s[4 * c + 2] = v[2]; s[4 * c + 3] = v[3];
    }

    float invd[16];
    float ent = 0.0f;
    #pragma unroll
    for (int k = 0; k < 16; ++k) {
        Gt[k * RSA + li] = s[k];                    // publish residual column k
        f4 c0 = *(const f4*)&Gt[k * RSA + 0];
        f4 c1 = *(const f4*)&Gt[k * RSA + 4];
        f4 c2 = *(const f4*)&Gt[k * RSA + 8];
        f4 c3 = *(const f4*)&Gt[k * RSA + 12];
        float cc[16] = { c0[0], c0[1], c0[2], c0[3], c1[0], c1[1], c1[2], c1[3],
                         c2[0], c2[1], c2[2], c2[3], c3[0], c3[1], c3[2], c3[3] };
        float dkk = fmaxf(cc[k], 1e-20f);
        float inv = rsqrtf(dkk);
        invd[k] = inv;
        if (li == k) ent = 0.5f * __logf(dkk);
        s[k] *= inv;
        #pragma unroll
        for (int j = k + 1; j < 16; ++j)
            s[j] = fmaf(-s[k], cc[j] * inv, s[j]);  // trailing update
    }
    // Gt now holds residual columns; G[m][i] = Gt[i*RSA+m] * invd[i]

    // Y = G^{-T} (lane li owns column li, all in registers), u = G^{-T} ns
    float y[16], uu[16];
    {
        float nsv[16];
        const f4* nsp = (const f4*)&ns[(size_t)t * 16];
        f4 n0 = nsp[0], n1 = nsp[1], n2 = nsp[2], n3 = nsp[3];
        nsv[0] = n0[0]; nsv[1] = n0[1]; nsv[2] = n0[2]; nsv[3] = n0[3];
        nsv[4] = n1[0]; nsv[5] = n1[1]; nsv[6] = n1[2]; nsv[7] = n1[3];
        nsv[8] = n2[0]; nsv[9] = n2[1]; nsv[10] = n2[2]; nsv[11] = n2[3];
        nsv[12] = n3[0]; nsv[13] = n3[1]; nsv[14] = n3[2]; nsv[15] = n3[3];
        #pragma unroll
        for (int ii = 0; ii < 16; ++ii) {
            const int i = 15 - ii;
            f4 c0 = *(const f4*)&Gt[i * RSA + 0];
            f4 c1 = *(const f4*)&Gt[i * RSA + 4];
            f4 c2 = *(const f4*)&Gt[i * RSA + 8];
            f4 c3 = *(const f4*)&Gt[i * RSA + 12];
            float cc[16] = { c0[0], c0[1], c0[2], c0[3], c1[0], c1[1], c1[2], c1[3],
                             c2[0], c2[1], c2[2], c2[3], c3[0], c3[1], c3[2], c3[3] };
            float sy = 0.f, su = 0.f;
            #pragma unroll
            for (int m = i + 1; m < 16; ++m) {
                sy = fmaf(cc[m], y[m], sy);         // cc[m]*invd[i] = G[m][i]
                su = fmaf(cc[m], uu[m], su);
            }
            float inv = invd[i];
            y[i]  = (((li == i) ? 1.0f : 0.0f) - inv * sy) * inv;
            uu[i] = (nsv[i] - inv * su) * inv;
        }
    }
    // publish Y column li (f32), overwriting the slot (G fully consumed)
    #pragma unroll
    for (int c = 0; c < 4; ++c) {
        f4 v = { y[4 * c + 0], y[4 * c + 1], y[4 * c + 2], y[4 * c + 3] };
        *(f4*)&Gt[li * RSA + c * 4] = v;
    }
    if (li == 0) {
        f4* U4 = (f4*)&Ubuf[(size_t)t * 16];
        f4 u0 = { uu[0], uu[1], uu[2], uu[3] };
        f4 u1 = { uu[4], uu[5], uu[6], uu[7] };
        f4 u2 = { uu[8], uu[9], uu[10], uu[11] };
        f4 u3 = { uu[12], uu[13], uu[14], uu[15] };
        U4[0] = u0; U4[1] = u1; U4[2] = u2; U4[3] = u3;
    }

    // ---- per-wave: W = Y Y^T, N^T = (-C1) W, coalesced bf16 N store ----
    {
        unsigned int* Ypw = &Yp[wv * SLOT];
        for (int tt = 0; tt < 4; ++tt) {
            int sl = wv * 4 + tt;
            int tc = t0 + sl;
            const float* Gs = &Gc[sl * SLOT];
            // transpose Y (col-major f32) -> Yrow packed hi|lo u32, row-major
            uint4 yw;
            yw.x = packhl(Gs[(quad * 4 + 0) * RSA + col]);
            yw.y = packhl(Gs[(quad * 4 + 1) * RSA + col]);
            yw.z = packhl(Gs[(quad * 4 + 2) * RSA + col]);
            yw.w = packhl(Gs[(quad * 4 + 3) * RSA + col]);
            *(uint4*)&Ypw[col * RSA + quad * 4] = yw;
            // W = Yr Yr^T (Gram: both operands read row l&15 of Yrow)
            uint4 r0 = *(const uint4*)&Ypw[col * RSA + (quad & 1) * 8];
            uint4 r1 = *(const uint4*)&Ypw[col * RSA + (quad & 1) * 8 + 4];
            bh8 yh, yl; unpk8(r0, r1, yh, yl);
            f4 accW = { 0.f, 0.f, 0.f, 0.f };
            accW = __builtin_amdgcn_mfma_f32_16x16x32_bf16((quad < 2) ? yh : yl, yh, accW, 0, 0, 0);
            accW = __builtin_amdgcn_mfma_f32_16x16x32_bf16(yh, (quad < 2) ? yl : zero8, accW, 0, 0, 0);
            // store W col-major packed (overwrites Yrow; reads completed before MFMA)
            uint4 ww;
            ww.x = packhl(accW[0]); ww.y = packhl(accW[1]);
            ww.z = packhl(accW[2]); ww.w = packhl(accW[3]);
            *(uint4*)&Ypw[col * RSA + quad * 4] = ww;
            // N^T = (-C1) * W
            uint4 q0 = *(const uint4*)&Agl[sl * SLOT + col * RSA + (quad & 1) * 8];
            uint4 q1 = *(const uint4*)&Agl[sl * SLOT + col * RSA + (quad & 1) * 8 + 4];
            bh8 ch, clo; unpk8(q0, q1, ch, clo);
            uint4 v0 = *(const uint4*)&Ypw[col * RSA + (quad & 1) * 8];
            uint4 v1 = *(const uint4*)&Ypw[col * RSA + (quad & 1) * 8 + 4];
            bh8 wh, wl; unpk8(v0, v1, wh, wl);
            f4 accN = { 0.f, 0.f, 0.f, 0.f };
            accN = __builtin_amdgcn_mfma_f32_16x16x32_bf16((quad < 2) ? ch : clo, wh, accN, 0, 0, 0);
            accN = __builtin_amdgcn_mfma_f32_16x16x32_bf16(ch, (quad < 2) ? wl : zero8, accN, 0, 0, 0);
            if (tc < T_LEN - 1) {
                // D lane holds N^T[q*4+r][col] = N[col][q*4+r] -> contiguous ushort4
                ushort4 nv;
                nv.x = f2bf(accN[0]); nv.y = f2bf(accN[1]);
                nv.z = f2bf(accN[2]); nv.w = f2bf(accN[3]);
                *(ushort4*)&Nbuf[(size_t)tc * 256 + col * 16 + quad * 4] = nv;
            }
        }
    }

    // entropy: reduce across the wave, one atomic per wave
    float esum = ent;
    #pragma unroll
    for (int off = 1; off < 64; off <<= 1)
        esum += __shfl_xor(esum, off, 64);
    if ((tid & 63) == 0) atomicAdd(entOut, -esum);
}

// ---- backward recurrence x_t = u_t + N_t x_{t+1}, overlapped chunks ----
__global__ __launch_bounds__(64, 1)
void vilds_stage2(const unsigned short* __restrict__ Nbuf, const float* __restrict__ Ubuf,
                  const float* __restrict__ PXbuf, float* __restrict__ out)
{
    const int lane = threadIdx.x;
    const int i  = lane & 15;   // output row
    const int gq = lane >> 4;   // k-quarter (4 columns each)
    const int a  = blockIdx.x * K2;
    int ts = a + K2 - 1 + W2;
    if (ts > T_LEN - 1) ts = T_LEN - 1;

    float x = Ubuf[(size_t)ts * 16 + i];   // exact at t=T-1, truncated start otherwise
    if (ts < a + K2 && gq == 0)
        out[1 + (size_t)ts * 16 + i] = x + PXbuf[(size_t)ts * 16 + i];

    ushort4 nb[PF]; float ub[PF], pxb[PF];
    #pragma unroll
    for (int q = 0; q < PF; ++q) {
        int tt = ts - 1 - q;
        if (tt >= a) {
            nb[q]  = *(const ushort4*)&Nbuf[(size_t)tt * 256 + i * 16 + gq * 4];
            ub[q]  = Ubuf[(size_t)tt * 16 + i];
            pxb[q] = PXbuf[(size_t)tt * 16 + i];
        }
    }

    for (int tb = ts - 1; tb >= a; tb -= PF) {
        #pragma unroll
        for (int q = 0; q < PF; ++q) {
            int t = tb - q;
            if (t >= a) {
                ushort4 nr = nb[q]; float ut = ub[q]; float pxt = pxb[q];
                int tp = t - PF;
                if (tp >= a) {   // prefetch PF steps ahead
                    nb[q]  = *(const ushort4*)&Nbuf[(size_t)tp * 256 + i * 16 + gq * 4];
                    ub[q]  = Ubuf[(size_t)tp * 16 + i];
                    pxb[q] = PXbuf[(size_t)tp * 16 + i];
                }
                float n0 = bf2f(nr.x), n1 = bf2f(nr.y), n2 = bf2f(nr.z), n3 = bf2f(nr.w);
                float x0 = __shfl(x, 4 * gq + 0, 16);
                float x1 = __shfl(x, 4 * gq + 1, 16);
                float x2 = __shfl(x, 4 * gq + 2, 16);
                float x3 = __shfl(x, 4 * gq + 3, 16);
                float pr = fmaf(n0, x0, n1 * x1);
                pr = fmaf(n2, x2, pr);
                pr = fmaf(n3, x3, pr);
                pr += __shfl_xor(pr, 16);
                pr += __shfl_xor(pr, 32);
                x = ut + pr;                       // x_t[i], replicated over gq
                if (t < a + K2 && gq == 0)
                    out[1 + (size_t)t * 16 + i] = x + pxt;
            }
        }
    }
}

extern "C" void kernel_launch(void* const* d_in, const int* in_sizes, int n_in,
                              void* d_out, int out_size, void* d_ws, size_t ws_size,
                              hipStream_t stream)
{
    const float* data = (const float*)d_in[0];
    const float* Wmu  = (const float*)d_in[1];
    const float* bmu  = (const float*)d_in[2];
    const float* WL   = (const float*)d_in[3];
    const float* bL   = (const float*)d_in[4];
    const float* WLx  = (const float*)d_in[5];
    const float* bLx  = (const float*)d_in[6];
    const float* ns   = (const float*)d_in[7];
    float* out = (float*)d_out;

    unsigned short* Nbuf = (unsigned short*)d_ws;                 // T*256 bf16
    float* Ubuf  = (float*)(Nbuf + (size_t)T_LEN * 256);          // T*16 f32
    float* PXbuf = Ubuf + (size_t)T_LEN * 16;                     // T*16 f32
    short* Wsw   = (short*)(PXbuf + (size_t)T_LEN * 16);          // 66*512 bf16

    hipMemsetAsync(d_out, 0, sizeof(float), stream); // zero entropy accumulator
    wswz_kernel<<<dim3(132), dim3(256), 0, stream>>>(Wmu, WL, WLx, Wsw);
    vilds_fused<<<dim3(T_LEN / 16), dim3(256), 0, stream>>>(
        data, Wsw, bmu, bL, bLx, ns, Nbuf, Ubuf, PXbuf, out);
    vilds_stage2<<<dim3(T_LEN / K2), dim3(64), 0, stream>>>(Nbuf, Ubuf, PXbuf, out);
}